// Round 9
// baseline (114.836 us; speedup 1.0000x reference)
//
#include <hip/hip_runtime.h>
#include <math.h>

#define N_ 2048
#define K_ 512
#define J_ 256
#define REP 5   // DIAGNOSTIC: idempotent main-loop repeat to lift the kernel above
                // the 40.5us poison fills so its rocprof counters become visible.
                // max/min re-merging identical products is a no-op; set to 1 later.

typedef float f32x4 __attribute__((ext_vector_type(4)));
typedef __attribute__((address_space(3))) float       lds_f;
typedef const __attribute__((address_space(1))) float glb_f;

// 2 muls + 1 max3 + 1 min3 per 2 products = 2.0 VALU ops/product.
#define MAX3(acc, a, b) asm("v_max3_f32 %0, %0, %1, %2" : "+v"(acc) : "v"(a), "v"(b))
#define MIN3(acc, a, b) asm("v_min3_f32 %0, %0, %1, %2" : "+v"(acc) : "v"(a), "v"(b))

// Grid 256 x 512 thr (8 waves), 1 block/CU (96 KB LDS), 2 waves/SIMD.
// Block tile 64n x 32j x K=512 staged in 4 dbuf slices of 128 k.
// Lane grid 8x8 (rn,cj); per-lane tile 8n x 4j (rows rn+8i, cols cj+8jj):
// per 4-k quad 12 ds_read_b128 feed 256 VALU insts -> LDS/VALU 1.125 (R8: 1.5).
// XOR swizzle slot^(row&7): reads hit 8 distinct bank-quads (8-lane broadcast
// within each); staged via linear-dest global_load_lds + inverse-swizzled source.
__global__ __launch_bounds__(512) void mam_fused10(
    const float* __restrict__ x, const float* __restrict__ w,
    const float* __restrict__ bias, float* __restrict__ out)
{
    __shared__ __align__(16) float sm[24576];   // 96 KB: x[2][64][128] | w[2][32][128]

    const int t    = threadIdx.x;
    const int lane = t & 63;
    const int kq   = __builtin_amdgcn_readfirstlane(t >> 6);   // wave 0..7

    // XCD-chunked bijective swizzle (256 = 8 * 32).
    const int wg0 = (int)blockIdx.x;
    const int wg  = (wg0 & 7) * 32 + (wg0 >> 3);
    const int bx  = wg & 7;             // j-block (32 cols)
    const int by  = wg >> 3;            // n-block (64 rows)
    const int n0  = by * 64;
    const int j0  = bx * 32;

    const int rn = lane >> 3;           // 0..7
    const int cj = lane & 7;            // 0..7

    float mx[8][4], mn[8][4];
#pragma unroll
    for (int i = 0; i < 8; ++i)
#pragma unroll
        for (int jj = 0; jj < 4; ++jj) {
            mx[i][jj] = -__builtin_inff();
            mn[i][jj] =  __builtin_inff();
        }

    // ---- Staging: slice s = 128 k. One global_load_lds(16B) = 1KB = 2 rows.
    // LDS slot tslot of row r holds element slot tslot^(r&7) (inverse swizzle
    // on the per-lane SOURCE address; dest stays linear).
#define STAGE(buf, s)                                                          \
    {                                                                          \
        const int kb = (s) * 128;                                              \
        _Pragma("unroll")                                                      \
        for (int u = 0; u < 4; ++u) {   /* x: 32 loads, 4 per wave */          \
            const int li  = kq * 4 + u;                                        \
            const int row = 2 * li + (lane >> 5);                              \
            __builtin_amdgcn_global_load_lds(                                  \
                (glb_f*)(x + (size_t)(n0 + row) * K_ + kb                      \
                         + (((lane & 31) ^ (row & 7)) << 2)),                  \
                (lds_f*)(sm + (buf) * 8192 + li * 256), 16, 0, 0);             \
        }                                                                      \
        _Pragma("unroll")                                                      \
        for (int u = 0; u < 2; ++u) {   /* w: 16 loads, 2 per wave */          \
            const int wi  = kq * 2 + u;                                        \
            const int col = 2 * wi + (lane >> 5);                              \
            __builtin_amdgcn_global_load_lds(                                  \
                (glb_f*)(w + (size_t)(j0 + col) * K_ + kb                      \
                         + (((lane & 31) ^ (col & 7)) << 2)),                  \
                (lds_f*)(sm + 16384 + (buf) * 4096 + wi * 256), 16, 0, 0);     \
        }                                                                      \
    }

    // ---- Compute one slice: wave kq's 16 k = 4 quads x {12 reads + 256 VALU}.
#define COMP(buf)                                                              \
    for (int rep = 0; rep < REP; ++rep) {                                      \
        _Pragma("unroll")                                                      \
        for (int q = 0; q < 4; ++q) {                                          \
            const int sb = kq * 4 + q;          /* 16B-slot base in row */     \
            const int xo = (buf) * 8192 + rn * 128 + ((sb ^ rn) << 2);         \
            const int wo = 16384 + (buf) * 4096 + cj * 128 + ((sb ^ cj) << 2); \
            f32x4 xv[8], wv[4];                                                \
            _Pragma("unroll")                                                  \
            for (int i = 0; i < 8; ++i)                                        \
                xv[i] = *(const f32x4*)&sm[xo + i * 1024];                     \
            _Pragma("unroll")                                                  \
            for (int jj = 0; jj < 4; ++jj)                                     \
                wv[jj] = *(const f32x4*)&sm[wo + jj * 1024];                   \
            _Pragma("unroll")                                                  \
            for (int i = 0; i < 8; ++i)                                        \
                _Pragma("unroll")                                              \
                for (int jj = 0; jj < 4; ++jj) {                               \
                    const f32x4 a = xv[i], b = wv[jj];                         \
                    const float p0 = a.x * b.x, p1 = a.y * b.y;                \
                    const float p2 = a.z * b.z, p3 = a.w * b.w;                \
                    MAX3(mx[i][jj], p0, p1); MAX3(mx[i][jj], p2, p3);          \
                    MIN3(mn[i][jj], p0, p1); MIN3(mn[i][jj], p2, p3);          \
                }                                                              \
        }                                                                      \
        asm volatile("" ::: "memory");  /* defeat load-CSE across reps */      \
    }

    STAGE(0, 0);
    __syncthreads();
    STAGE(1, 1);  COMP(0);
    __syncthreads();
    STAGE(0, 2);  COMP(1);
    __syncthreads();
    STAGE(1, 3);  COMP(0);
    __syncthreads();
                  COMP(1);
    __syncthreads();   // LDS about to be reused for the combine

#undef STAGE
#undef COMP

    // ---- Combine 8 k-chunks, two 16-col halves (cb[8][64][17] float2 = 68KB).
    float2* cb = (float2*)sm;
#pragma unroll
    for (int h = 0; h < 2; ++h) {
#pragma unroll
        for (int i = 0; i < 8; ++i)
#pragma unroll
            for (int jh = 0; jh < 2; ++jh) {
                const int jj = 2 * h + jh;
                float2 v; v.x = mx[i][jj]; v.y = mn[i][jj];
                cb[(kq * 64 + rn + 8 * i) * 17 + cj + 8 * jh] = v;
            }
        __syncthreads();
#pragma unroll
        for (int e = 0; e < 2; ++e) {
            const int o   = t + e * 512;       // 1024 outputs per half
            const int row = o >> 4;
            const int c16 = o & 15;
            float a = -__builtin_inff(), b = __builtin_inff();
#pragma unroll
            for (int c = 0; c < 8; ++c) {
                const float2 v = cb[(c * 64 + row) * 17 + c16];
                a = fmaxf(a, v.x);
                b = fminf(b, v.y);
            }
            const int j = j0 + 16 * h + c16;
            out[(size_t)(n0 + row) * J_ + j] = a + b + bias[j];
        }
        __syncthreads();
    }
}

extern "C" void kernel_launch(void* const* d_in, const int* in_sizes, int n_in,
                              void* d_out, int out_size, void* d_ws, size_t ws_size,
                              hipStream_t stream) {
    const float* x    = (const float*)d_in[0];
    const float* w    = (const float*)d_in[1];
    const float* bias = (const float*)d_in[2];
    float* out = (float*)d_out;

    dim3 grid(256);   // 32 n-blocks x 8 j-blocks, XCD-swizzled in-kernel
    mam_fused10<<<grid, 512, 0, stream>>>(x, w, bias, out);
}

// Round 10
// 71.545 us; speedup vs baseline: 1.6051x; 1.6051x over previous
//
#include <hip/hip_runtime.h>
#include <math.h>

#define N_ 2048
#define K_ 512
#define J_ 256

typedef float f32x4 __attribute__((ext_vector_type(4)));
typedef __attribute__((address_space(3))) float       lds_f;
typedef const __attribute__((address_space(1))) float glb_f;

// 2 muls + 1 max3 + 1 min3 per 2 products = 2.0 VALU ops/product.
#define MAX3(acc, a, b) asm("v_max3_f32 %0, %0, %1, %2" : "+v"(acc) : "v"(a), "v"(b))
#define MIN3(acc, a, b) asm("v_min3_f32 %0, %0, %1, %2" : "+v"(acc) : "v"(a), "v"(b))

// Grid 256 x 512 thr (8 waves), 1 block/CU (96 KB LDS), 2 waves/SIMD.
// Geometry as R9 (verified): block 64n x 32j x K=512 in 4 dbuf slices of 128k;
// lane grid 8x8 (rn,cj), per-lane tile 8n x 4j; XOR-swizzled LDS (conflicts
// measured dead: 262K cyc total). R9 PMC showed DS and VALU SERIALIZED
// (70.9us @ REP=5 = sum of pipes, not max): compiler emitted read->wait->compute
// per quad with no read-ahead (VGPR=88). This version pipelines explicitly:
// one asm block per quad = 12 ds_read_b128 + s_waitcnt lgkmcnt(12) (waits for
// the PREVIOUS quad's reads; DS in-order per wave) + sched_barrier(0) so the
// consumer VALU cannot hoist above the wait (rule #18). Register sets A/B
// alternate. Staging is vmcnt-only -> lgkm counts are exact.
__global__ __launch_bounds__(512, 2) void mam_fused11(
    const float* __restrict__ x, const float* __restrict__ w,
    const float* __restrict__ bias, float* __restrict__ out)
{
    __shared__ __align__(16) float sm[24576];   // 96 KB: x[2][64][128] | w[2][32][128]

    const int t    = threadIdx.x;
    const int lane = t & 63;
    const int kq   = __builtin_amdgcn_readfirstlane(t >> 6);   // wave 0..7

    // XCD-chunked bijective swizzle (256 = 8 * 32).
    const int wg0 = (int)blockIdx.x;
    const int wg  = (wg0 & 7) * 32 + (wg0 >> 3);
    const int bx  = wg & 7;             // j-block (32 cols)
    const int by  = wg >> 3;            // n-block (64 rows)
    const int n0  = by * 64;
    const int j0  = bx * 32;

    const int rn = lane >> 3;           // 0..7
    const int cj = lane & 7;            // 0..7

    float mx[8][4], mn[8][4];
#pragma unroll
    for (int i = 0; i < 8; ++i)
#pragma unroll
        for (int jj = 0; jj < 4; ++jj) {
            mx[i][jj] = -__builtin_inff();
            mn[i][jj] =  __builtin_inff();
        }

    // ---- Staging (verified in R9): slice s = 128 k; element [row][k] at LDS
    // slot (k>>2)^(row&7) via linear dest + inverse-swizzled per-lane source.
#define STAGE(buf, s)                                                          \
    {                                                                          \
        const int kb = (s) * 128;                                              \
        _Pragma("unroll")                                                      \
        for (int u = 0; u < 4; ++u) {   /* x: 32 loads, 4 per wave */          \
            const int li  = kq * 4 + u;                                        \
            const int row = 2 * li + (lane >> 5);                              \
            __builtin_amdgcn_global_load_lds(                                  \
                (glb_f*)(x + (size_t)(n0 + row) * K_ + kb                      \
                         + (((lane & 31) ^ (row & 7)) << 2)),                  \
                (lds_f*)(sm + (buf) * 8192 + li * 256), 16, 0, 0);             \
        }                                                                      \
        _Pragma("unroll")                                                      \
        for (int u = 0; u < 2; ++u) {   /* w: 16 loads, 2 per wave */          \
            const int wi  = kq * 2 + u;                                        \
            const int col = 2 * wi + (lane >> 5);                              \
            __builtin_amdgcn_global_load_lds(                                  \
                (glb_f*)(w + (size_t)(j0 + col) * K_ + kb                      \
                         + (((lane & 31) ^ (col & 7)) << 2)),                  \
                (lds_f*)(sm + 16384 + (buf) * 4096 + wi * 256), 16, 0, 0);     \
        }                                                                      \
    }

    f32x4 AXv[8], AWv[4], BXv[8], BWv[4];   // double-buffered read sets

    // One quad's reads (+optional counted wait) in a single ordered asm block.
    // x rows rn+8i at xa + i*4096 B; w cols cj+8jj at wa + jj*4096 B.
#define READQ(Xv, Wv, xa, wa, WCNT)                                            \
    asm volatile(                                                              \
        "ds_read_b128 %0, %12\n\t"                                             \
        "ds_read_b128 %1, %12 offset:4096\n\t"                                 \
        "ds_read_b128 %2, %12 offset:8192\n\t"                                 \
        "ds_read_b128 %3, %12 offset:12288\n\t"                                \
        "ds_read_b128 %4, %12 offset:16384\n\t"                                \
        "ds_read_b128 %5, %12 offset:20480\n\t"                                \
        "ds_read_b128 %6, %12 offset:24576\n\t"                                \
        "ds_read_b128 %7, %12 offset:28672\n\t"                                \
        "ds_read_b128 %8, %13\n\t"                                             \
        "ds_read_b128 %9, %13 offset:4096\n\t"                                 \
        "ds_read_b128 %10, %13 offset:8192\n\t"                                \
        "ds_read_b128 %11, %13 offset:12288\n\t"                               \
        WCNT                                                                   \
        : "=&v"(Xv[0]), "=&v"(Xv[1]), "=&v"(Xv[2]), "=&v"(Xv[3]),              \
          "=&v"(Xv[4]), "=&v"(Xv[5]), "=&v"(Xv[6]), "=&v"(Xv[7]),              \
          "=&v"(Wv[0]), "=&v"(Wv[1]), "=&v"(Wv[2]), "=&v"(Wv[3])               \
        : "v"(xa), "v"(wa));                                                   \
    __builtin_amdgcn_sched_barrier(0);

#define COMPQ(Xv, Wv)                                                          \
    _Pragma("unroll")                                                          \
    for (int i = 0; i < 8; ++i)                                                \
        _Pragma("unroll")                                                      \
        for (int jj = 0; jj < 4; ++jj) {                                       \
            const f32x4 a = Xv[i], b = Wv[jj];                                 \
            const float p0 = a.x * b.x, p1 = a.y * b.y;                        \
            const float p2 = a.z * b.z, p3 = a.w * b.w;                        \
            MAX3(mx[i][jj], p0, p1); MAX3(mx[i][jj], p2, p3);                  \
            MIN3(mn[i][jj], p0, p1); MIN3(mn[i][jj], p2, p3);                  \
        }

    // One slice: 4 quads, read-ahead depth 1 (sets A/B alternate).
    // LDS byte addrs: x: buf*32768 + rn*512 + ((slot^rn)<<4);
    //                 w: 65536 + buf*16384 + cj*512 + ((slot^cj)<<4).
#define COMP(buf)                                                              \
    {                                                                          \
        const unsigned xb0 = (buf) * 32768u + (unsigned)(rn * 512);            \
        const unsigned wb0 = 65536u + (buf) * 16384u + (unsigned)(cj * 512);   \
        const unsigned xa0 = xb0 + (unsigned)((((kq * 4 + 0) ^ rn)) << 4);     \
        const unsigned wa0 = wb0 + (unsigned)((((kq * 4 + 0) ^ cj)) << 4);     \
        const unsigned xa1 = xb0 + (unsigned)((((kq * 4 + 1) ^ rn)) << 4);     \
        const unsigned wa1 = wb0 + (unsigned)((((kq * 4 + 1) ^ cj)) << 4);     \
        const unsigned xa2 = xb0 + (unsigned)((((kq * 4 + 2) ^ rn)) << 4);     \
        const unsigned wa2 = wb0 + (unsigned)((((kq * 4 + 2) ^ cj)) << 4);     \
        const unsigned xa3 = xb0 + (unsigned)((((kq * 4 + 3) ^ rn)) << 4);     \
        const unsigned wa3 = wb0 + (unsigned)((((kq * 4 + 3) ^ cj)) << 4);     \
        READQ(AXv, AWv, xa0, wa0, "");                                         \
        READQ(BXv, BWv, xa1, wa1, "s_waitcnt lgkmcnt(12)\n\t");                \
        COMPQ(AXv, AWv);                                                       \
        READQ(AXv, AWv, xa2, wa2, "s_waitcnt lgkmcnt(12)\n\t");                \
        COMPQ(BXv, BWv);                                                       \
        READQ(BXv, BWv, xa3, wa3, "s_waitcnt lgkmcnt(12)\n\t");                \
        COMPQ(AXv, AWv);                                                       \
        asm volatile("s_waitcnt lgkmcnt(0)");                                  \
        __builtin_amdgcn_sched_barrier(0);                                     \
        COMPQ(BXv, BWv);                                                       \
    }

    STAGE(0, 0);
    __syncthreads();
    STAGE(1, 1);  COMP(0);
    __syncthreads();
    STAGE(0, 2);  COMP(1);
    __syncthreads();
    STAGE(1, 3);  COMP(0);
    __syncthreads();
                  COMP(1);
    __syncthreads();   // LDS about to be reused for the combine

#undef STAGE
#undef READQ
#undef COMPQ
#undef COMP

    // ---- Combine 8 k-chunks, two 16-col halves (cb[8][64][17] float2 = 68KB).
    float2* cb = (float2*)sm;
#pragma unroll
    for (int h = 0; h < 2; ++h) {
#pragma unroll
        for (int i = 0; i < 8; ++i)
#pragma unroll
            for (int jh = 0; jh < 2; ++jh) {
                const int jj = 2 * h + jh;
                float2 v; v.x = mx[i][jj]; v.y = mn[i][jj];
                cb[(kq * 64 + rn + 8 * i) * 17 + cj + 8 * jh] = v;
            }
        __syncthreads();
#pragma unroll
        for (int e = 0; e < 2; ++e) {
            const int o   = t + e * 512;       // 1024 outputs per half
            const int row = o >> 4;
            const int c16 = o & 15;
            float a = -__builtin_inff(), b = __builtin_inff();
#pragma unroll
            for (int c = 0; c < 8; ++c) {
                const float2 v = cb[(c * 64 + row) * 17 + c16];
                a = fmaxf(a, v.x);
                b = fminf(b, v.y);
            }
            const int j = j0 + 16 * h + c16;
            out[(size_t)(n0 + row) * J_ + j] = a + b + bias[j];
        }
        __syncthreads();
    }
}

extern "C" void kernel_launch(void* const* d_in, const int* in_sizes, int n_in,
                              void* d_out, int out_size, void* d_ws, size_t ws_size,
                              hipStream_t stream) {
    const float* x    = (const float*)d_in[0];
    const float* w    = (const float*)d_in[1];
    const float* bias = (const float*)d_in[2];
    float* out = (float*)d_out;

    dim3 grid(256);   // 32 n-blocks x 8 j-blocks, XCD-swizzled in-kernel
    mam_fused11<<<grid, 512, 0, stream>>>(x, w, bias, out);
}